// Round 2
// baseline (170.058 us; speedup 1.0000x reference)
//
#include <hip/hip_runtime.h>
#include <hip/hip_bf16.h>

#define N_NODES 50000
#define DEG 16
#define NE 800000
#define HID 128
#define NH 32
#define ECH 64
#define NG 64
#define LN_EPS 1e-5f

typedef __bf16 bf16x8 __attribute__((ext_vector_type(8)));
typedef float f32x4 __attribute__((ext_vector_type(4)));

__device__ __forceinline__ unsigned short f2bf(float f) {
  unsigned int u = __float_as_uint(f);
  u += 0x7FFFu + ((u >> 16) & 1u);          // round-to-nearest-even
  return (unsigned short)(u >> 16);
}
__device__ __forceinline__ unsigned int pack2(float a, float b) {
  return (unsigned int)f2bf(a) | ((unsigned int)f2bf(b) << 16);
}
// sum over the 16-lane DPP row (our 16 edges) via row_ror rotations
__device__ __forceinline__ float rowsum16(float v) {
  v += __int_as_float(__builtin_amdgcn_update_dpp(0, __float_as_int(v), 0x121, 0xF, 0xF, true));
  v += __int_as_float(__builtin_amdgcn_update_dpp(0, __float_as_int(v), 0x122, 0xF, 0xF, true));
  v += __int_as_float(__builtin_amdgcn_update_dpp(0, __float_as_int(v), 0x124, 0xF, 0xF, true));
  v += __int_as_float(__builtin_amdgcn_update_dpp(0, __float_as_int(v), 0x128, 0xF, 0xF, true));
  return v;
}

// ---------------------------------------------------------------- prep ------
// Repack Wq|Wkv into MFMA fragment order WBf[n(16)][kk(4)][lane(64)][8] and
// Wdk into Wdkf[n2(8)][kk(2)][lane(64)][8]; zero graph accumulators.
__global__ void prep_kernel(const float* __restrict__ Wq, const float* __restrict__ Wkv,
                            const float* __restrict__ Wdk,
                            unsigned short* __restrict__ WBf,
                            unsigned short* __restrict__ Wdkf,
                            float* __restrict__ gsum) {
  int b = blockIdx.x, t = threadIdx.x;
  if (b < 16) {
    int n = b;
    for (int idx = t; idx < 2048; idx += 256) {
      int j = idx & 7, l = (idx >> 3) & 63, kk = idx >> 9;
      int col = n * 16 + (l & 15);
      int k = kk * 32 + (l >> 4) * 8 + j;
      float v = (col < HID) ? Wq[k * HID + col] : Wkv[k * HID + (col - HID)];
      WBf[((n * 4 + kk) * 64 + l) * 8 + j] = f2bf(v);
    }
  } else if (b < 24) {
    int n2 = b - 16;
    for (int idx = t; idx < 1024; idx += 256) {
      int j = idx & 7, l = (idx >> 3) & 63, kk = idx >> 9;
      int col = n2 * 16 + (l & 15);
      int k = kk * 32 + (l >> 4) * 8 + j;
      Wdkf[((n2 * 2 + kk) * 64 + l) * 8 + j] = f2bf(Wdk[k * HID + col]);
    }
  } else {
    int chunk = b - 24;
    for (int i = chunk * 1024 + t; i < (chunk + 1) * 1024; i += 256)
      gsum[i] = 0.0f;
  }
}

// ------------------------------------------------------------- node pass ----
__global__ __launch_bounds__(256) void node_kernel(
    const float* __restrict__ x, const float* __restrict__ bq,
    const float* __restrict__ bkv, const float* __restrict__ lng,
    const float* __restrict__ lnb, const unsigned short* __restrict__ WBf,
    float* __restrict__ qout, unsigned short* __restrict__ kout) {
  __shared__ __align__(16) unsigned short xn[64 * HID];
  int t = threadIdx.x;
  int node0 = blockIdx.x * 64;
  {
    int row = t >> 2, q4 = t & 3;
    int c0 = q4 * 32;
    int node = node0 + row;
    float v[32];
    if (node < N_NODES) {
      const float4* xp = (const float4*)(x + node * HID + c0);
#pragma unroll
      for (int i = 0; i < 8; i++) {
        float4 f = xp[i];
        v[4 * i] = f.x; v[4 * i + 1] = f.y; v[4 * i + 2] = f.z; v[4 * i + 3] = f.w;
      }
    } else {
#pragma unroll
      for (int i = 0; i < 32; i++) v[i] = 0.f;
    }
    float s = 0.f;
#pragma unroll
    for (int i = 0; i < 32; i++) s += v[i];
    s += __shfl_xor(s, 1); s += __shfl_xor(s, 2);
    float m = s * (1.0f / HID);
    float sq = 0.f;
#pragma unroll
    for (int i = 0; i < 32; i++) { float d = v[i] - m; sq += d * d; }
    sq += __shfl_xor(sq, 1); sq += __shfl_xor(sq, 2);
    float rstd = rsqrtf(sq * (1.0f / HID) + LN_EPS);
#pragma unroll
    for (int ch = 0; ch < 4; ch++) {
      float w0[8];
#pragma unroll
      for (int j = 0; j < 8; j++) {
        int c = c0 + ch * 8 + j;
        w0[j] = (v[ch * 8 + j] - m) * rstd * lng[c] + lnb[c];
      }
      uint4 u;
      u.x = pack2(w0[0], w0[1]); u.y = pack2(w0[2], w0[3]);
      u.z = pack2(w0[4], w0[5]); u.w = pack2(w0[6], w0[7]);
      int byte = row * 256 + ((c0 * 2 + ch * 16) ^ ((row & 7) << 4));
      *(uint4*)((char*)xn + byte) = u;
    }
  }
  __syncthreads();
  int w = t >> 6, l = t & 63;
  int arow = w * 16 + (l & 15);
  bf16x8 a[4];
#pragma unroll
  for (int kk = 0; kk < 4; kk++) {
    int byte = arow * 256 + ((kk * 64 + (l >> 4) * 16) ^ ((arow & 7) << 4));
    a[kk] = *(const bf16x8*)((const char*)xn + byte);
  }
  f32x4 acc[16];
#pragma unroll
  for (int n = 0; n < 16; n++) acc[n] = (f32x4){0.f, 0.f, 0.f, 0.f};
#pragma unroll
  for (int n = 0; n < 16; n++)
#pragma unroll
    for (int kk = 0; kk < 4; kk++) {
      bf16x8 bfr = *(const bf16x8*)(WBf + ((n * 4 + kk) * 64 + l) * 8);
      acc[n] = __builtin_amdgcn_mfma_f32_16x16x32_bf16(a[kk], bfr, acc[n], 0, 0, 0);
    }
#pragma unroll
  for (int n = 0; n < 16; n++) {
    int col = n * 16 + (l & 15);
    float bias = (col < HID) ? bq[col] : bkv[col - HID];
#pragma unroll
    for (int r = 0; r < 4; r++) {
      int node = node0 + w * 16 + (l >> 4) * 4 + r;
      if (node < N_NODES) {
        float vv = acc[n][r] + bias;
        if (col < HID) qout[node * HID + col] = vv;
        else kout[node * HID + (col - HID)] = f2bf(vv);
      }
    }
  }
}

// ------------------------------------------------------------- edge pass ----
// 4 nodes (64 edges) per block, 1 node per wave. Swapped-operand MFMA gives
// each lane (edge = l&15, head = n*4 + (l>>4), d = reg). Head-dot + silu are
// fully in-lane; edge-sum is a 16-lane DPP row_ror reduction.
__global__ __launch_bounds__(256) void edge_kernel(
    const float* __restrict__ x, const float* __restrict__ ea,
    const int* __restrict__ src_arr, const int* __restrict__ batch,
    const float* __restrict__ bdk, const float* __restrict__ lng,
    const float* __restrict__ lnb, const float* __restrict__ qg,
    const unsigned short* __restrict__ kbf,
    const unsigned short* __restrict__ Wdkf, float* __restrict__ gsum) {
  __shared__ __align__(16) unsigned short ea_s[64 * ECH];  // 8 KB swizzled
  __shared__ __align__(16) float q_s[4 * HID];
  __shared__ __align__(16) float h_s[4 * 132];
  __shared__ __align__(16) float bdk_s[HID];
  __shared__ __align__(16) float g_s[HID];
  __shared__ __align__(16) float b_s[HID];
  __shared__ int src_s[64];
  __shared__ int b4[4];
  int t = threadIdx.x;
  int node0 = blockIdx.x * 4;
  int e0 = node0 * DEG;

  if (t < 64) src_s[t] = src_arr[e0 + t];
  if (t >= 64 && t < 68) b4[t - 64] = batch[node0 + (t - 64)];
  if (t < HID) { bdk_s[t] = bdk[t]; g_s[t] = lng[t]; b_s[t] = lnb[t]; }
  q_s[t] = qg[node0 * HID + t];
  q_s[t + 256] = qg[node0 * HID + 256 + t];
  {
    int row = t >> 2, q4 = t & 3;
    int c0 = q4 * 16;
    const float4* p = (const float4*)(ea + (size_t)(e0 + row) * ECH + c0);
#pragma unroll
    for (int ch = 0; ch < 2; ch++) {
      float4 f0 = p[ch * 2], f1 = p[ch * 2 + 1];
      uint4 u;
      u.x = pack2(f0.x, f0.y); u.y = pack2(f0.z, f0.w);
      u.z = pack2(f1.x, f1.y); u.w = pack2(f1.z, f1.w);
      int byte = row * 128 + ((c0 * 2 + ch * 16) ^ ((row & 7) << 4));
      *(uint4*)((char*)ea_s + byte) = u;
    }
  }
  __syncthreads();

  int w = t >> 6, l = t & 63;
  int el = l & 15;                      // edge within this wave's node
  int eh = l >> 4;                      // d-chunk row (head sub-group)
  int ni = node0 + w;

  // B fragments: ea rows of this node's 16 edges
  int arow = w * 16 + el;
  bf16x8 bfr[2];
#pragma unroll
  for (int kk = 0; kk < 2; kk++) {
    int byte = arow * 128 + ((kk * 64 + eh * 16) ^ ((arow & 7) << 4));
    bfr[kk] = *(const bf16x8*)((const char*)ea_s + byte);
  }
  // dk^T = Wdk^T (A) x ea^T (B): acc[n][r] = dk[e0 + el][n*16 + eh*4 + r]
  f32x4 acc[8];
#pragma unroll
  for (int n = 0; n < 8; n++) acc[n] = (f32x4){0.f, 0.f, 0.f, 0.f};
#pragma unroll
  for (int n = 0; n < 8; n++)
#pragma unroll
    for (int kk = 0; kk < 2; kk++) {
      bf16x8 af = *(const bf16x8*)(Wdkf + ((n * 2 + kk) * 64 + l) * 8);
      acc[n] = __builtin_amdgcn_mfma_f32_16x16x32_bf16(af, bfr[kk], acc[n], 0, 0, 0);
    }

  // k gather: this lane's edge row, its 8B slice per n
  const unsigned short* kr = kbf + (size_t)src_s[w * 16 + el] * HID;
  uint2 kg[8];
#pragma unroll
  for (int n = 0; n < 8; n++) kg[n] = *(const uint2*)(kr + n * 16 + eh * 4);

  f32x4 h1[8];
#pragma unroll
  for (int n = 0; n < 8; n++) {
    const int cb = n * 16 + eh * 4;
    f32x4 qv = *(const f32x4*)&q_s[w * HID + cb];
    f32x4 bd = *(const f32x4*)&bdk_s[cb];
    float k0 = __uint_as_float(kg[n].x << 16);
    float k1 = __uint_as_float(kg[n].x & 0xFFFF0000u);
    float k2 = __uint_as_float(kg[n].y << 16);
    float k3 = __uint_as_float(kg[n].y & 0xFFFF0000u);
    float d0 = acc[n][0] + bd[0];
    float d1 = acc[n][1] + bd[1];
    float d2 = acc[n][2] + bd[2];
    float d3 = acc[n][3] + bd[3];
    float s = qv[0] * k0 * d0 + qv[1] * k1 * d1 + qv[2] * k2 * d2 + qv[3] * k3 * d3;
    float at = s * __builtin_amdgcn_rcpf(1.0f + __expf(-s));   // silu
    float m0 = rowsum16(k0 * at);
    float m1 = rowsum16(k1 * at);
    float m2 = rowsum16(k2 * at);
    float m3 = rowsum16(k3 * at);
    f32x4 xv = *(const f32x4*)(x + (size_t)ni * HID + cb);
    h1[n] = (f32x4){xv[0] + m0 * 0.0625f, xv[1] + m1 * 0.0625f,
                    xv[2] + m2 * 0.0625f, xv[3] + m3 * 0.0625f};
  }
  // LayerNorm over the node's 128 channels (rows partition channels)
  float ss = 0.f;
#pragma unroll
  for (int n = 0; n < 8; n++) ss += h1[n][0] + h1[n][1] + h1[n][2] + h1[n][3];
  ss += __shfl_xor(ss, 16); ss += __shfl_xor(ss, 32);
  float mean = ss * (1.0f / HID);
  float vv = 0.f;
#pragma unroll
  for (int n = 0; n < 8; n++) {
    float d0 = h1[n][0] - mean, d1 = h1[n][1] - mean;
    float d2 = h1[n][2] - mean, d3 = h1[n][3] - mean;
    vv += d0 * d0 + d1 * d1 + d2 * d2 + d3 * d3;
  }
  vv += __shfl_xor(vv, 16); vv += __shfl_xor(vv, 32);
  float rstd = rsqrtf(vv * (1.0f / HID) + LN_EPS);
  if (el < 8) {                          // lane el writes n = el (all dup'd)
    int n = el;
    const int cb = n * 16 + eh * 4;
    f32x4 g4 = *(const f32x4*)&g_s[cb];
    f32x4 bb = *(const f32x4*)&b_s[cb];
    f32x4 xv = *(const f32x4*)(x + (size_t)ni * HID + cb);
    f32x4 ho;
#pragma unroll
    for (int r = 0; r < 4; r++)
      ho[r] = xv[r] + (h1[n][r] - mean) * rstd * g4[r] + bb[r];
    *(f32x4*)&h_s[w * 132 + cb] = ho;
  }
  __syncthreads();
  if (t < HID) {                         // run-length-compress by graph
    int c = t;
    float accu = h_s[c];
#pragma unroll
    for (int nn = 1; nn < 4; nn++) {
      if (b4[nn] == b4[nn - 1]) accu += h_s[nn * 132 + c];
      else { atomicAdd(&gsum[b4[nn - 1] * HID + c], accu); accu = h_s[nn * 132 + c]; }
    }
    atomicAdd(&gsum[b4[3] * HID + c], accu);
  }
}

// -------------------------------------------------------------- readout -----
__global__ void readout_kernel(const float* __restrict__ gsum,
                               const int* __restrict__ batch,
                               const float* __restrict__ Wout,
                               const float* __restrict__ bout,
                               float* __restrict__ out) {
  int g = blockIdx.x, l = threadIdx.x;
  int lo = 0, hi = N_NODES;
  while (lo < hi) { int mid = (lo + hi) >> 1; if (batch[mid] < g) lo = mid + 1; else hi = mid; }
  int lo2 = lo, hi2 = N_NODES;
  while (lo2 < hi2) { int mid = (lo2 + hi2) >> 1; if (batch[mid] < g + 1) lo2 = mid + 1; else hi2 = mid; }
  int cnt = lo2 - lo; if (cnt < 1) cnt = 1;
  float v = gsum[g * HID + l] * Wout[l] + gsum[g * HID + 64 + l] * Wout[64 + l];
#pragma unroll
  for (int s = 32; s >= 1; s >>= 1) v += __shfl_xor(v, s);
  if (l == 0) out[g] = v / (float)cnt + bout[0];
}

// ---------------------------------------------------------------------------
extern "C" void kernel_launch(void* const* d_in, const int* in_sizes, int n_in,
                              void* d_out, int out_size, void* d_ws, size_t ws_size,
                              hipStream_t stream) {
  const float* x         = (const float*)d_in[0];
  const float* edge_attr = (const float*)d_in[1];
  const float* Wq        = (const float*)d_in[2];
  const float* bq        = (const float*)d_in[3];
  const float* Wkv       = (const float*)d_in[4];
  const float* bkv       = (const float*)d_in[5];
  const float* Wdk       = (const float*)d_in[6];
  const float* bdk       = (const float*)d_in[7];
  const float* ln_in_g   = (const float*)d_in[8];
  const float* ln_in_b   = (const float*)d_in[9];
  const float* ln_out_g  = (const float*)d_in[10];
  const float* ln_out_b  = (const float*)d_in[11];
  const float* Wout      = (const float*)d_in[12];
  const float* bout      = (const float*)d_in[13];
  const int* edge_index  = (const int*)d_in[14];   // [2][E]: src then dst
  const int* batch       = (const int*)d_in[15];
  float* outp = (float*)d_out;

  char* ws = (char*)d_ws;
  float* qbuf          = (float*)ws;
  unsigned short* kbuf = (unsigned short*)(ws + 25600000);
  unsigned short* WBf  = (unsigned short*)(ws + 25600000 + 12800000);
  unsigned short* Wdkf = (unsigned short*)(ws + 25600000 + 12800000 + 65536);
  float* gsum          = (float*)(ws + 25600000 + 12800000 + 65536 + 16384);

  prep_kernel<<<32, 256, 0, stream>>>(Wq, Wkv, Wdk, WBf, Wdkf, gsum);
  node_kernel<<<(N_NODES + 63) / 64, 256, 0, stream>>>(x, bq, bkv, ln_in_g, ln_in_b,
                                                       WBf, qbuf, kbuf);
  edge_kernel<<<N_NODES / 4, 256, 0, stream>>>(x, edge_attr, edge_index, batch, bdk,
                                               ln_out_g, ln_out_b, qbuf, kbuf, Wdkf, gsum);
  readout_kernel<<<NG, 64, 0, stream>>>(gsum, batch, Wout, bout, outp);
}